// Round 1
// 403.371 us; speedup vs baseline: 1.0097x; 1.0097x over previous
//
#include <hip/hip_runtime.h>
#include <math.h>

#define H 4096
#define E 64
#define BMROWS 32      // rows per block
#define NT 256         // 4 waves; each wave owns a k-quarter
#define KQ 1024        // k per wave
#define BK 32          // k per window (one mfma k-step)
#define NWIN (KQ / BK) // 32 windows

typedef short bf16x8 __attribute__((ext_vector_type(8)));
typedef float f32x4  __attribute__((ext_vector_type(4)));

__device__ __forceinline__ unsigned f2bf_rne_u(float f) {
    unsigned u = __float_as_uint(f);
    return (u + 0x7fffu + ((u >> 16) & 1u)) >> 16;
}

// ---- kernel 1: w fp32 [64][4096] -> w_hi, w_lo bf16 (bits in ushort) ----
__global__ __launch_bounds__(256) void convert_w(const float* __restrict__ w,
                                                 unsigned short* __restrict__ wh,
                                                 unsigned short* __restrict__ wl) {
    const int i = (blockIdx.x * 256 + threadIdx.x) * 4;
    float4 v = *(const float4*)(w + i);
    float vv[4] = {v.x, v.y, v.z, v.w};
    unsigned hh[4], ll[4];
#pragma unroll
    for (int j = 0; j < 4; ++j) {
        hh[j] = f2bf_rne_u(vv[j]);
        float r = vv[j] - __uint_as_float(hh[j] << 16);
        ll[j] = __float_as_uint(r) >> 16;   // truncation: fine for residual
    }
    ushort4 h, l;
    h.x = (unsigned short)hh[0]; h.y = (unsigned short)hh[1];
    h.z = (unsigned short)hh[2]; h.w = (unsigned short)hh[3];
    l.x = (unsigned short)ll[0]; l.y = (unsigned short)ll[1];
    l.z = (unsigned short)ll[2]; l.w = (unsigned short)ll[3];
    *(ushort4*)(wh + i) = h;
    *(ushort4*)(wl + i) = l;
}

// 5-op/elem hi/lo split. Numerically IDENTICAL to the previous version:
// hi = RNE-bf16 of v (t>>16), hi-as-float = t & 0xffff0000 == (t>>16)<<16,
// lo = truncated bf16 of the exact residual. Saves the shl/shr round-trips;
// the (short) pair-inserts compile to v_perm.
__device__ __forceinline__ void cvt8(const float4 a, const float4 b,
                                     bf16x8& hi, bf16x8& lo) {
    float v[8] = {a.x, a.y, a.z, a.w, b.x, b.y, b.z, b.w};
#pragma unroll
    for (int i = 0; i < 8; ++i) {
        const unsigned u = __float_as_uint(v[i]);
        const unsigned t = u + 0x7fffu + ((u >> 16) & 1u); // rounded bf16 in t[31:16]
        const float    r = v[i] - __uint_as_float(t & 0xffff0000u);
        hi[i] = (short)(t >> 16);
        lo[i] = (short)(__float_as_uint(r) >> 16);
    }
}

// ---- kernel 2: fused hi/lo bf16 MFMA GEMM + top-2 + softmax ----
// Block: 32 rows (2 mfma m-tiles) x 64 experts (4 n-tiles). 4 waves split K.
// x: 4-buffer round-robin register prefetch, 3 windows deep (12 KiB/wave in
// flight). w: double-buffered registers (no per-window snapshot copies).
__global__ __launch_bounds__(NT, 2) void router_kernel(
    const float* __restrict__ x,
    const unsigned short* __restrict__ wh,
    const unsigned short* __restrict__ wl,
    float* __restrict__ out, int M)
{
    __shared__ __align__(16) f32x4 merge[8][4][64];   // [acc idx][wave][lane]

    const int t    = threadIdx.x;
    const int lane = t & 63;
    const int wk   = t >> 6;        // k-quarter 0..3
    const int m0   = blockIdx.x * BMROWS;
    const int col  = lane & 15;
    const int quad = lane >> 4;     // 0..3

    const int kbase = wk * KQ + quad * 8;

    const float* xp0 = x + (size_t)(m0 + col) * H + kbase;
    const float* xp1 = x + (size_t)(m0 + 16 + col) * H + kbase;
    const unsigned short* whp = wh + (size_t)col * H + kbase;
    const unsigned short* wlp = wl + (size_t)col * H + kbase;

    f32x4 acc[2][4];
#pragma unroll
    for (int mt = 0; mt < 2; ++mt)
#pragma unroll
        for (int nt = 0; nt < 4; ++nt)
            acc[mt][nt] = (f32x4){0.0f, 0.0f, 0.0f, 0.0f};

    // x prefetch ring (distance 3) and w ping-pong — all names compile-time
    // so everything stays in VGPRs (no runtime-indexed arrays -> no scratch).
    float4 x0[2][2], x1[2][2], x2[2][2], x3[2][2];
    uint4  wAh[4], wAl[4], wBh[4], wBl[4];

    auto loadx_into = [&](int win, float4 (&xb)[2][2]) {
        const int k = win * BK;
        xb[0][0] = *(const float4*)(xp0 + k);
        xb[0][1] = *(const float4*)(xp0 + k + 4);
        xb[1][0] = *(const float4*)(xp1 + k);
        xb[1][1] = *(const float4*)(xp1 + k + 4);
    };
    auto loadw_into = [&](int win, uint4 (&wh_)[4], uint4 (&wl_)[4]) {
        const int k = win * BK;
#pragma unroll
        for (int nt = 0; nt < 4; ++nt) {
            wh_[nt] = *(const uint4*)(whp + (size_t)(nt * 16) * H + k);
            wl_[nt] = *(const uint4*)(wlp + (size_t)(nt * 16) * H + k);
        }
    };

    // One window: issue prefetches first (x at distance 3, w at distance 1),
    // then convert + MFMA on already-resident registers. MFMA reads w buffers
    // directly (in-order issue => no WAR copy needed before the next loadw).
    auto step = [&](int win, float4 (&xc)[2][2], float4 (&xpref)[2][2],
                    uint4 (&whc)[4], uint4 (&wlc)[4],
                    uint4 (&whn)[4], uint4 (&wln)[4]) {
        if (win + 3 < NWIN) loadx_into(win + 3, xpref);
        if (win + 1 < NWIN) loadw_into(win + 1, whn, wln);
        bf16x8 ah[2], al[2];
        cvt8(xc[0][0], xc[0][1], ah[0], al[0]);
        cvt8(xc[1][0], xc[1][1], ah[1], al[1]);
#pragma unroll
        for (int nt = 0; nt < 4; ++nt) {
            const bf16x8 bh = __builtin_bit_cast(bf16x8, whc[nt]);
            const bf16x8 bl = __builtin_bit_cast(bf16x8, wlc[nt]);
#pragma unroll
            for (int mt = 0; mt < 2; ++mt) {
                acc[mt][nt] = __builtin_amdgcn_mfma_f32_16x16x32_bf16(
                    ah[mt], bh, acc[mt][nt], 0, 0, 0);
                acc[mt][nt] = __builtin_amdgcn_mfma_f32_16x16x32_bf16(
                    ah[mt], bl, acc[mt][nt], 0, 0, 0);
                acc[mt][nt] = __builtin_amdgcn_mfma_f32_16x16x32_bf16(
                    al[mt], bh, acc[mt][nt], 0, 0, 0);
            }
        }
    };

    loadx_into(0, x0);
    loadx_into(1, x1);
    loadx_into(2, x2);
    loadw_into(0, wAh, wAl);

#pragma unroll 1
    for (int win = 0; win < NWIN; win += 4) {
        step(win,     x0, x3, wAh, wAl, wBh, wBl);
        step(win + 1, x1, x0, wBh, wBl, wAh, wAl);
        step(win + 2, x2, x1, wAh, wAl, wBh, wBl);
        step(win + 3, x3, x2, wBh, wBl, wAh, wAl);
    }

    // ---- cross-wave k-merge via LDS (conflict-free layout) ----
#pragma unroll
    for (int mt = 0; mt < 2; ++mt)
#pragma unroll
        for (int nt = 0; nt < 4; ++nt)
            merge[mt * 4 + nt][wk][lane] = acc[mt][nt];
    __syncthreads();

    if (wk >= 2) return;
    const int mt = wk;              // wave 0 -> m-tile 0, wave 1 -> m-tile 1

    f32x4 a2[4];
#pragma unroll
    for (int nt = 0; nt < 4; ++nt) {
        f32x4 s = merge[mt * 4 + nt][0][lane];
#pragma unroll
        for (int w = 1; w < 4; ++w)
            s += merge[mt * 4 + nt][w][lane];
        a2[nt] = s;
    }

    float* logits   = out;
    float* idx_out  = out + (size_t)M * E;
    float* prob_out = idx_out + (size_t)M * 2;

    const int mrow = m0 + mt * 16 + quad * 4;
#pragma unroll
    for (int r = 0; r < 4; ++r) {
#pragma unroll
        for (int nt = 0; nt < 4; ++nt)
            logits[(size_t)(mrow + r) * E + nt * 16 + col] = a2[nt][r];

        // per-lane top-2 over its 4 experts (ascending index)
        float v1 = a2[0][r], v2 = -INFINITY;
        int   i1 = col,      i2 = 0x7fffffff;
#pragma unroll
        for (int nt = 1; nt < 4; ++nt) {
            const float v = a2[nt][r];
            const int   e = nt * 16 + col;
            if (v > v1)      { v2 = v1; i2 = i1; v1 = v; i1 = e; }
            else if (v > v2) { v2 = v;  i2 = e; }
        }
        // butterfly merge across the 16-lane row group
#pragma unroll
        for (int mask = 1; mask < 16; mask <<= 1) {
            const float ov1 = __shfl_xor(v1, mask);
            const float ov2 = __shfl_xor(v2, mask);
            const int   oi1 = __shfl_xor(i1, mask);
            const int   oi2 = __shfl_xor(i2, mask);
            const bool afirst = (v1 > ov1) || (v1 == ov1 && i1 < oi1);
            float nv1, nv2; int ni1, ni2;
            if (afirst) {
                nv1 = v1; ni1 = i1;
                const bool s = (v2 > ov1) || (v2 == ov1 && i2 < oi1);
                nv2 = s ? v2 : ov1; ni2 = s ? i2 : oi1;
            } else {
                nv1 = ov1; ni1 = oi1;
                const bool s = (ov2 > v1) || (ov2 == v1 && oi2 < i1);
                nv2 = s ? ov2 : v1; ni2 = s ? oi2 : i1;
            }
            v1 = nv1; v2 = nv2; i1 = ni1; i2 = ni2;
        }
        if (col == 0) {
            const int m = mrow + r;
            const float e2 = __expf(v2 - v1);   // <= 1
            const float d  = 1.0f + e2;
            *(float2*)(idx_out  + (size_t)m * 2) = make_float2((float)i1, (float)i2);
            *(float2*)(prob_out + (size_t)m * 2) = make_float2(1.0f / d, e2 / d);
        }
    }
}

extern "C" void kernel_launch(void* const* d_in, const int* in_sizes, int n_in,
                              void* d_out, int out_size, void* d_ws, size_t ws_size,
                              hipStream_t stream) {
    const float* x = (const float*)d_in[0];
    const float* w = (const float*)d_in[1];
    unsigned short* wh = (unsigned short*)d_ws;           // 512 KB
    unsigned short* wl = wh + (size_t)E * H;              // 512 KB
    const int M = in_sizes[0] / H;                        // 16384 rows

    hipLaunchKernelGGL(convert_w, dim3((E * H) / 1024), dim3(256), 0, stream,
                       w, wh, wl);
    hipLaunchKernelGGL(router_kernel, dim3(M / BMROWS), dim3(NT), 0, stream,
                       x, wh, wl, (float*)d_out, M);
}